// Round 1
// baseline (234.042 us; speedup 1.0000x reference)
//
#include <hip/hip_runtime.h>

typedef float vf2  __attribute__((ext_vector_type(2)));
typedef float v128f __attribute__((ext_vector_type(128)));

__device__ __forceinline__ vf2 cmulv(vf2 a, vf2 b){
  vf2 br; br.x = -b.y; br.y = b.x;
  return a.x*b + a.y*br;
}

#define ROWS 66   // transpose-buffer row stride in float2 (64 + 2 pad -> bank stagger)
#define FENCE() asm volatile("" ::: "memory")

// merged-diagonal angle for wire j of diagonal d (wave-uniform); d, j compile-time
// (used only by the upfront scsl build path below via W[] directly)

// 6 RY gates on the reg-domain bits of the big-vector state (sl, par may be runtime)
#define GATES6(sl, par) do{ \
  _Pragma("unroll") \
  for (int lb = 0; lb < 6; lb++){ \
    const int wire_ = (par) ? (5 - lb) : (11 - lb); \
    vf2 cs_ = scsl[(sl)*12 + wire_]; \
    const float c_ = cs_.x, sn_ = cs_.y; \
    _Pragma("unroll") \
    for (int w0 = 0; w0 < 64; w0++){ \
      if (w0 & (1 << lb)) continue; \
      const int w1 = w0 | (1 << lb); \
      vf2 a_, b_, r0_, r1_; \
      a_.x = st[2*w0]; a_.y = st[2*w0+1]; \
      b_.x = st[2*w1]; b_.y = st[2*w1+1]; \
      r0_ = c_*a_ - sn_*b_; \
      r1_ = sn_*a_ + c_*b_; \
      st[2*w0] = r0_.x; st[2*w0+1] = r0_.y; \
      st[2*w1] = r1_.x; st[2*w1+1] = r1_.y; \
    } \
  } \
}while(0)

// Two-phase 64x64 lane<->reg transpose through a 32-row LDS buffer (half the old
// footprint -> 8 blocks/CU).  Phase A moves the cross blocks: lanes<32 export regs
// 32..63 / import new regs 32..63 (which they just exported -> no hazard, no stash);
// lanes>=32 symmetric.  Phase B moves the diagonal blocks.  All st[] indices are
// compile-time; only LDS addresses depend on the lane.  Per-wave in-order LDS pipe
// gives cross-lane RAW/WAR ordering; FENCE() stops the compiler from reordering the
// (provably column-disjoint) accesses across phases.
#define TRANSPOSE() do{ \
  if (u < 32){ \
    _Pragma("unroll") \
    for (int w = 32; w < 64; w++){ vf2 t_; t_.x = st[2*w]; t_.y = st[2*w+1]; \
      xbuf[(w-32) * ROWS + u] = t_; } \
  } else { \
    _Pragma("unroll") \
    for (int w = 0; w < 32; w++){ vf2 t_; t_.x = st[2*w]; t_.y = st[2*w+1]; \
      xbuf[w * ROWS + u] = t_; } \
  } \
  FENCE(); \
  if (u < 32){ \
    _Pragma("unroll") \
    for (int t = 0; t < 16; t++){ \
      float4 f_ = ((const float4*)&xbuf[u * ROWS + 32])[t]; \
      st[64+4*t] = f_.x; st[64+4*t+1] = f_.y; st[64+4*t+2] = f_.z; st[64+4*t+3] = f_.w; } \
  } else { \
    _Pragma("unroll") \
    for (int t = 0; t < 16; t++){ \
      float4 f_ = ((const float4*)&xbuf[(u-32) * ROWS])[t]; \
      st[4*t] = f_.x; st[4*t+1] = f_.y; st[4*t+2] = f_.z; st[4*t+3] = f_.w; } \
  } \
  FENCE(); \
  if (u < 32){ \
    _Pragma("unroll") \
    for (int w = 0; w < 32; w++){ vf2 t_; t_.x = st[2*w]; t_.y = st[2*w+1]; \
      xbuf[w * ROWS + u] = t_; } \
  } else { \
    _Pragma("unroll") \
    for (int w = 32; w < 64; w++){ vf2 t_; t_.x = st[2*w]; t_.y = st[2*w+1]; \
      xbuf[(w-32) * ROWS + u] = t_; } \
  } \
  FENCE(); \
  if (u < 32){ \
    _Pragma("unroll") \
    for (int t = 0; t < 16; t++){ \
      float4 f_ = ((const float4*)&xbuf[u * ROWS])[t]; \
      st[4*t] = f_.x; st[4*t+1] = f_.y; st[4*t+2] = f_.z; st[4*t+3] = f_.w; } \
  } else { \
    _Pragma("unroll") \
    for (int t = 0; t < 16; t++){ \
      float4 f_ = ((const float4*)&xbuf[(u-32) * ROWS + 32])[t]; \
      st[64+4*t] = f_.x; st[64+4*t+1] = f_.y; st[64+4*t+2] = f_.z; st[64+4*t+3] = f_.w; } \
  } \
  FENCE(); \
}while(0)

// merged diagonal (runtime par): reg part from tabs1, lane part from ltab1,
// cross CZ terms inline
#define DIAG(par) do{ \
  vf2 lp_ = ltab1[u]; \
  vf2 lpn_ = -lp_; \
  const int u0_ = u & 1, u1_ = (u >> 1) & 1, u4_ = (u >> 4) & 1, u5_ = (u >> 5) & 1; \
  _Pragma("unroll") \
  for (int w = 0; w < 64; w++){ \
    vf2 dph_ = tabs1[w]; \
    int sx_; \
    if (par) sx_ = ((w & 1) * u5_) ^ (((w >> 5) & 1) * u0_); \
    else     sx_ = (((w >> 5) & 1) * u1_) ^ (((w >> 4) & 1) * u0_) \
                 ^ (((w >> 1) & 1) * u5_) ^ ((w & 1) * u4_); \
    vf2 a_; a_.x = st[2*w]; a_.y = st[2*w+1]; \
    vf2 t_ = cmulv(a_, dph_); \
    vf2 r_ = cmulv(t_, sx_ ? lpn_ : lp_); \
    st[2*w] = r_.x; st[2*w+1] = r_.y; \
  } \
}while(0)

__global__ __attribute__((amdgpu_flat_work_group_size(64,64)))
__attribute__((amdgpu_waves_per_eu(2)))
void qiddm_wave(const float* __restrict__ gx,
                const float* __restrict__ gcw,
                const float* __restrict__ gcb,
                const float* __restrict__ gw1,
                const float* __restrict__ glw,
                const float* __restrict__ glb,
                float* __restrict__ gout)
{
  // One wave per sample; 4096-amp state in ONE ext_vector (mem2reg-guaranteed regs).
  // L0 layout: lane u = idx bits 11..6 (wires 0..5), reg w = idx bits 5..0 (wires 6..11)
  // L1 layout: lane u = idx bits 5..0,  reg w = idx bits 11..6
  // LDS budget: 16896 + 512 + 512 + 576 = 18496 B -> 8 blocks/CU (entire grid resident)
  __shared__ vf2 xbuf[32 * ROWS];   // 16896 B two-phase transpose buffer (aliases conv image)
  __shared__ vf2 tabs1[64];         // reg-domain diagonal table (current d only, JIT-built)
  __shared__ vf2 ltab1[64];         // lane-domain diagonal factors (current d only)
  __shared__ vf2 scsl[72];          // (cos, sin) of theta/2 per (sublayer, wire)

  const int u = threadIdx.x;        // lane 0..63
  const int bid = blockIdx.x;

  float xr[12];                     // circuit inputs / expvals (constant-indexed only)

  // ---------- conv 3x3 s2 p1 + bias + GAP ----------
  {
    float* img = (float*)xbuf;      // 4096 B < 16896 B
#pragma unroll
    for (int i = 0; i < 4; i++){
      float4 q4 = ((const float4*)gx)[(size_t)bid * 256 + i * 64 + u];
      ((float4*)img)[i * 64 + u] = q4;
    }
    float p[4][9];
#pragma unroll
    for (int i = 0; i < 4; i++){
      int pos = u + 64 * i, oi = pos >> 4, oj = pos & 15;
#pragma unroll
      for (int ki = 0; ki < 3; ki++)
#pragma unroll
        for (int kj = 0; kj < 3; kj++){
          int ri = 2*oi - 1 + ki, cj = 2*oj - 1 + kj;
          p[i][ki*3+kj] = (ri >= 0 && ri < 32 && cj >= 0 && cj < 32) ? img[ri*32+cj] : 0.0f;
        }
    }
#pragma unroll
    for (int q = 0; q < 12; q++){
      float a = 0.0f;
#pragma unroll
      for (int e = 0; e < 9; e++){
        float wv = gcw[q*9+e];                  // uniform -> scalarized
#pragma unroll
        for (int i = 0; i < 4; i++) a += p[i][e] * wv;
      }
#pragma unroll
      for (int off = 32; off; off >>= 1) a += __shfl_xor(a, off);
      xr[q] = gcb[q] + a * (1.0f/256.0f);
    }
  }

#pragma unroll 1
  for (int n = 0; n < 2; n++){
    const float* W = gw1 + n * 216;

    // ---- RY cos/sin table (72 gates) ----
#pragma unroll
    for (int rep = 0; rep < 2; rep++){
      int e = u + rep * 64;
      if (e < 72){
        float sv, cv; __sincosf(0.5f * W[e*3+1], &sv, &cv);
        vf2 cs; cs.x = cv; cs.y = sv; scsl[e] = cs;
      }
    }

    // ---- circuit: |0>, 12 half-sublayer steps, measure ----
    v128f st;
#pragma unroll
    for (int w = 0; w < 64; w++){ st[2*w] = 0.f; st[2*w+1] = 0.f; }
    if (u == 0) st[0] = 1.f;                    // idx 0 = (lane 0, reg 0)

    GATES6(0, 0);                               // k=0: s0 on wires 6..11 (L0)
#pragma unroll 1
    for (int k = 1; k < 12; k++){
      const int sl  = k >> 1;
      const int par = ((k + 1) >> 1) & 1;
      if (k & 1){
        TRANSPOSE();                            // flip lane/reg domains
      } else {
        // ---- JIT build of diagonal d = sl (runtime, sequential 1..5) ----
        // par is wave-uniform -> uniform branch; xr[] indices compile-time in each arm
        const int dd = (sl >> 1) * 2;
        float ph_r = 0.f, ph_l = 0.f;
        if (par){                               // odd d: weights only
#pragma unroll
          for (int lb = 0; lb < 6; lb++){
            const float bit = (float)((u >> lb) & 1) - 0.5f;
            ph_r += (W[((dd+1)*12+(5-lb))*3+0] + W[(dd*12+(5-lb))*3+2]) * bit;
            ph_l += (W[((dd+1)*12+(11-lb))*3+0] + W[(dd*12+(11-lb))*3+2]) * bit;
          }
        } else {                                // even d: includes encoder angles xr
#pragma unroll
          for (int lb = 0; lb < 6; lb++){
            const float bit = (float)((u >> lb) & 1) - 0.5f;
            ph_r += (W[(dd*12+(11-lb))*3+0] + xr[11-lb] + W[((dd-1)*12+(11-lb))*3+2]) * bit;
            ph_l += (W[(dd*12+(5-lb))*3+0] + xr[5-lb] + W[((dd-1)*12+(5-lb))*3+2]) * bit;
          }
        }
        {
          const int r_ = par ? 1 : 2;
          int idx = par ? (u << 6) : u;         // reg-domain basis index
          int y = ((idx << r_) | (idx >> (12 - r_))) & 0xFFF;
          int s = __popc(idx & y) & 1;          // within-reg CZ parity
          float sv, cv; __sincosf(ph_r, &sv, &cv);
          vf2 e_; e_.x = cv; e_.y = sv; if (s) e_ = -e_;
          tabs1[u] = e_;
          idx = par ? u : (u << 6);             // lane-domain basis index
          y = ((idx << r_) | (idx >> (12 - r_))) & 0xFFF;
          s = __popc(idx & y) & 1;              // within-lane CZ parity
          __sincosf(ph_l, &sv, &cv);
          vf2 e2_; e2_.x = cv; e2_.y = sv; if (s) e2_ = -e2_;
          ltab1[u] = e2_;
        }
        FENCE();                                // build writes before DIAG broadcast reads
        DIAG(par);                              // D_sl before the sublayer's 2nd half
      }
      GATES6(sl, par);
    }

    // ---- measurement in L0 (final omega-diagonal is a pure phase: dropped) ----
    {
      float P = 0.f, mm[6] = {0.f,0.f,0.f,0.f,0.f,0.f};  // wires 6..11 (reg bits 5..0)
#pragma unroll
      for (int w = 0; w < 64; w++){
        float re = st[2*w], im = st[2*w+1];
        float pr = re*re + im*im;
        P += pr;
#pragma unroll
        for (int i = 0; i < 6; i++)
          mm[i] += ((w >> (5 - i)) & 1) ? -pr : pr;
      }
#pragma unroll
      for (int q = 0; q < 12; q++){
        float val = (q < 6) ? (((u >> (5 - q)) & 1) ? -P : P)   // wires 0..5 (lane bits)
                            : mm[q - 6];
#pragma unroll
        for (int off = 32; off; off >>= 1) val += __shfl_xor(val, off);
        xr[q] = val;                            // uniform across lanes after butterfly
      }
    }
  }

  // ---------- final linear ----------
  {
#pragma unroll
    for (int i = 0; i < 16; i++){
      int o = i * 64 + u;
      const float4* wr = (const float4*)(glw + o * 12);   // 48B rows, 16B aligned
      float4 w0 = wr[0], w1 = wr[1], w2 = wr[2];
      float a = glb[o];
      a += xr[0]*w0.x + xr[1]*w0.y + xr[2]*w0.z + xr[3]*w0.w;
      a += xr[4]*w1.x + xr[5]*w1.y + xr[6]*w1.z + xr[7]*w1.w;
      a += xr[8]*w2.x + xr[9]*w2.y + xr[10]*w2.z + xr[11]*w2.w;
      gout[(size_t)bid * 1024 + o] = a;
    }
  }
}

extern "C" void kernel_launch(void* const* d_in, const int* in_sizes, int n_in,
                              void* d_out, int out_size, void* d_ws, size_t ws_size,
                              hipStream_t stream)
{
  (void)n_in; (void)d_ws; (void)ws_size; (void)out_size;
  const float* x  = (const float*)d_in[0];
  const float* cw = (const float*)d_in[1];
  const float* cb = (const float*)d_in[2];
  const float* w1 = (const float*)d_in[3];
  const float* lw = (const float*)d_in[4];
  const float* lb = (const float*)d_in[5];
  float* out = (float*)d_out;
  const int nb = in_sizes[0] / 1024;   // 2048 samples, one wave each
  hipLaunchKernelGGL(qiddm_wave, dim3(nb), dim3(64), 0, stream,
                     x, cw, cb, w1, lw, lb, out);
}